// Round 1
// 979.182 us; speedup vs baseline: 1.0816x; 1.0816x over previous
//
#include <hip/hip_runtime.h>
#include <hip/hip_bf16.h>

typedef __attribute__((ext_vector_type(8))) __bf16 bf16x8;
typedef __attribute__((ext_vector_type(4))) float f32x4;
typedef __attribute__((ext_vector_type(4))) unsigned short u16x4;

#define NN 50000
#define TM1 16    // nodes per block, kernel 1  (50000/16 = 3125)
#define NODES2 8  // nodes per block, kernel 2 -> 64 point rows (50000/8 = 6250)

// ws layout (u16 elements unless noted):
//   0        : W0t bf16 [256 n][320 k]   (81920)
//   81920    : W1t bf16 [256 n][256 k]   (65536)
//   147456   : W2t bf16 [256 n][256 k]   (65536)
//   212992   : feats bf16 [50000][64]    (3,200,000)
//   3412992  : global split weights (bf16x3 hi/lo), 212992 elts:
//              +0      Wg0t_h [256 n][256 k]
//              +65536  Wg0t_l
//              +131072 Wg1t_h [128 n][256 k]
//              +163840 Wg1t_l
//              +196608 Wg2t_h [64 n][128 k]
//              +204800 Wg2t_l
//   total ws bytes: 7,251,968  (was 13.2 MB)

#define FEATS_OFF 212992
#define GW_OFF    3412992

__device__ __forceinline__ unsigned short f2bf(float f) {
    unsigned int u = __builtin_bit_cast(unsigned int, f);
    u = (u + 0x7FFFu + ((u >> 16) & 1u)) >> 16;   // RNE; inputs are finite
    return (unsigned short)u;
}
__device__ __forceinline__ float bf2f(unsigned short h) {
    return __builtin_bit_cast(float, (unsigned int)h << 16);
}

// ---------------------------------------------------------------------------
// Prep: point-MLP weights -> bf16 transposed; global-MLP weights -> split
// bf16 hi/lo transposed (for fp32-accurate MFMA via A_h*W_h + A_l*W_h + A_h*W_l)
// ---------------------------------------------------------------------------
__global__ __launch_bounds__(256) void k_prep(
    const float* __restrict__ W0, const float* __restrict__ W1,
    const float* __restrict__ W2,
    const float* __restrict__ Wg0, const float* __restrict__ Wg1,
    const float* __restrict__ Wg2,
    unsigned short* __restrict__ wbf)
{
    int idx = blockIdx.x * 256 + threadIdx.x;
    if (idx < 81920) {                       // W0t[n][k] = W0[k][n], k<320
        int n = idx / 320, k = idx - n * 320;
        wbf[idx] = f2bf(W0[(size_t)k * 256 + n]);
    } else if (idx < 147456) {               // W1t
        int e = idx - 81920;
        int n = e >> 8, k = e & 255;
        wbf[idx] = f2bf(W1[(size_t)k * 256 + n]);
    } else if (idx < 212992) {               // W2t
        int e = idx - 147456;
        int n = e >> 8, k = e & 255;
        wbf[idx] = f2bf(W2[(size_t)k * 256 + n]);
    } else if (idx < 319488) {               // global weights, split hi/lo
        int e = idx - 212992;                // 0 .. 106495
        float v; int oh, ol;
        if (e < 65536) {                     // Wg0t [256][256]
            int n = e >> 8, k = e & 255;
            v = Wg0[(size_t)k * 256 + n];
            oh = GW_OFF + e; ol = GW_OFF + 65536 + e;
        } else if (e < 98304) {              // Wg1t [128][256]
            int e2 = e - 65536;
            int n = e2 >> 8, k = e2 & 255;
            v = Wg1[(size_t)k * 128 + n];
            oh = GW_OFF + 131072 + e2; ol = GW_OFF + 163840 + e2;
        } else {                             // Wg2t [64][128]
            int e3 = e - 98304;
            int n = e3 >> 7, k = e3 & 127;
            v = Wg2[(size_t)k * 64 + n];
            oh = GW_OFF + 196608 + e3; ol = GW_OFF + 204800 + e3;
        }
        unsigned short h = f2bf(v);
        wbf[oh] = h;
        wbf[ol] = f2bf(v - bf2f(h));
    }
}

// ---------------------------------------------------------------------------
// Kernel 1: global feature MLP on MFMA (bf16x3 split precision, fp32-grade)
//           + decoder head (fp32 VALU) + cluster write
// ---------------------------------------------------------------------------
__global__ __launch_bounds__(256) void k_global(
    const float* __restrict__ x,
    const float* __restrict__ bg0, const float* __restrict__ bg1,
    const float* __restrict__ bg2,
    const float* __restrict__ Wdec, const float* __restrict__ bdec,
    const unsigned short* __restrict__ gw,
    unsigned short* __restrict__ feats_bf,
    float* __restrict__ out_rel,
    float* __restrict__ out_cluster)
{
    // LDS: 4*(16*264*2) + 2*(16*136*2) + 16*64*4 = 46592 B -> 3 blocks/CU
    __shared__ __attribute__((aligned(16))) unsigned short xh[TM1 * 264];
    __shared__ __attribute__((aligned(16))) unsigned short xl[TM1 * 264];
    __shared__ __attribute__((aligned(16))) unsigned short hh[TM1 * 264];
    __shared__ __attribute__((aligned(16))) unsigned short hl[TM1 * 264];
    __shared__ __attribute__((aligned(16))) unsigned short q1h[TM1 * 136];
    __shared__ __attribute__((aligned(16))) unsigned short q1l[TM1 * 136];
    __shared__ __attribute__((aligned(16))) float g2[TM1 * 64];

    const int tid  = threadIdx.x;
    const int lane = tid & 63;
    const int w    = tid >> 6;      // wave id 0..3
    const int quad = lane >> 4;     // 0..3
    const int l15  = lane & 15;
    const int blk  = blockIdx.x;

    // ---- stage 16 node rows, split fp32 -> bf16 hi + lo
    for (int e = tid; e < TM1 * 256; e += 256) {
        int r = e >> 8, c = e & 255;
        float v = x[(size_t)(blk * TM1 + r) * 256 + c];
        unsigned short h = f2bf(v);
        xh[r * 264 + c] = h;
        xl[r * 264 + c] = f2bf(v - bf2f(h));
    }
    __syncthreads();

    // ---- L0: 256 -> 256  (wave w owns cols [64w, 64w+64))
    {
        const unsigned short* Wh = gw;
        const unsigned short* Wl = gw + 65536;
        f32x4 acc[4];
        f32x4 z = {0.f, 0.f, 0.f, 0.f};
        #pragma unroll
        for (int t = 0; t < 4; ++t) acc[t] = z;
        for (int ks = 0; ks < 8; ++ks) {
            int k0 = ks * 32 + quad * 8;
            bf16x8 ah = *(const bf16x8*)&xh[l15 * 264 + k0];
            bf16x8 al = *(const bf16x8*)&xl[l15 * 264 + k0];
            #pragma unroll
            for (int t = 0; t < 4; ++t) {
                int n = w * 64 + t * 16 + l15;
                bf16x8 bh = *(const bf16x8*)(Wh + (size_t)n * 256 + k0);
                bf16x8 bl = *(const bf16x8*)(Wl + (size_t)n * 256 + k0);
                acc[t] = __builtin_amdgcn_mfma_f32_16x16x32_bf16(ah, bh, acc[t], 0, 0, 0);
                acc[t] = __builtin_amdgcn_mfma_f32_16x16x32_bf16(al, bh, acc[t], 0, 0, 0);
                acc[t] = __builtin_amdgcn_mfma_f32_16x16x32_bf16(ah, bl, acc[t], 0, 0, 0);
            }
        }
        #pragma unroll
        for (int t = 0; t < 4; ++t) {
            int col = w * 64 + t * 16 + l15;
            float bb = bg0[col];
            #pragma unroll
            for (int r = 0; r < 4; ++r) {
                int row = quad * 4 + r;
                float v = fmaxf(acc[t][r] + bb, 0.f);
                unsigned short h = f2bf(v);
                hh[row * 264 + col] = h;
                hl[row * 264 + col] = f2bf(v - bf2f(h));
            }
        }
    }
    __syncthreads();

    // ---- L1: 256 -> 128  (wave w owns cols [32w, 32w+32))
    {
        const unsigned short* Wh = gw + 131072;
        const unsigned short* Wl = gw + 163840;
        f32x4 acc[2];
        f32x4 z = {0.f, 0.f, 0.f, 0.f};
        acc[0] = z; acc[1] = z;
        for (int ks = 0; ks < 8; ++ks) {
            int k0 = ks * 32 + quad * 8;
            bf16x8 ah = *(const bf16x8*)&hh[l15 * 264 + k0];
            bf16x8 al = *(const bf16x8*)&hl[l15 * 264 + k0];
            #pragma unroll
            for (int t = 0; t < 2; ++t) {
                int n = w * 32 + t * 16 + l15;
                bf16x8 bh = *(const bf16x8*)(Wh + (size_t)n * 256 + k0);
                bf16x8 bl = *(const bf16x8*)(Wl + (size_t)n * 256 + k0);
                acc[t] = __builtin_amdgcn_mfma_f32_16x16x32_bf16(ah, bh, acc[t], 0, 0, 0);
                acc[t] = __builtin_amdgcn_mfma_f32_16x16x32_bf16(al, bh, acc[t], 0, 0, 0);
                acc[t] = __builtin_amdgcn_mfma_f32_16x16x32_bf16(ah, bl, acc[t], 0, 0, 0);
            }
        }
        #pragma unroll
        for (int t = 0; t < 2; ++t) {
            int col = w * 32 + t * 16 + l15;
            float bb = bg1[col];
            #pragma unroll
            for (int r = 0; r < 4; ++r) {
                int row = quad * 4 + r;
                float v = fmaxf(acc[t][r] + bb, 0.f);
                unsigned short h = f2bf(v);
                q1h[row * 136 + col] = h;
                q1l[row * 136 + col] = f2bf(v - bf2f(h));
            }
        }
    }
    __syncthreads();

    // ---- L2: 128 -> 64  (wave w owns cols [16w, 16w+16))
    {
        const unsigned short* Wh = gw + 196608;
        const unsigned short* Wl = gw + 204800;
        f32x4 acc = {0.f, 0.f, 0.f, 0.f};
        for (int ks = 0; ks < 4; ++ks) {
            int k0 = ks * 32 + quad * 8;
            bf16x8 ah = *(const bf16x8*)&q1h[l15 * 136 + k0];
            bf16x8 al = *(const bf16x8*)&q1l[l15 * 136 + k0];
            int n = w * 16 + l15;
            bf16x8 bh = *(const bf16x8*)(Wh + (size_t)n * 128 + k0);
            bf16x8 bl = *(const bf16x8*)(Wl + (size_t)n * 128 + k0);
            acc = __builtin_amdgcn_mfma_f32_16x16x32_bf16(ah, bh, acc, 0, 0, 0);
            acc = __builtin_amdgcn_mfma_f32_16x16x32_bf16(al, bh, acc, 0, 0, 0);
            acc = __builtin_amdgcn_mfma_f32_16x16x32_bf16(ah, bl, acc, 0, 0, 0);
        }
        int col = w * 16 + l15;
        float bb = bg2[col];
        #pragma unroll
        for (int r = 0; r < 4; ++r) {
            int row = quad * 4 + r;
            g2[row * 64 + col] = fmaxf(acc[r] + bb, 0.f);
        }
    }
    __syncthreads();

    // ---- feats -> ws as bf16 (k_points consumed bf16 anyway: bit-identical)
    {
        const float* src = g2 + tid * 4;
        u16x4 p;
        p[0] = f2bf(src[0]); p[1] = f2bf(src[1]);
        p[2] = f2bf(src[2]); p[3] = f2bf(src[3]);
        *(u16x4*)&feats_bf[(size_t)blk * (TM1 * 64) + tid * 4] = p;
    }

    // ---- decoder head: 16 nodes x 24 outputs, fp32
    for (int tt = tid; tt < TM1 * 24; tt += 256) {
        int m = tt / 24;
        int c = tt - m * 24;
        float acc = bdec[c];
        for (int i = 0; i < 64; ++i) acc += g2[m * 64 + i] * Wdec[i * 24 + c];
        out_rel[(size_t)blk * (TM1 * 24) + tt] = acc;
    }

    // ---- cluster ids (as float): 128 point rows per block
    if (tid < TM1 * 8) {
        out_cluster[(size_t)blk * (TM1 * 8) + tid] = (float)(blk * TM1 + (tid >> 3));
    }
}

// ---------------------------------------------------------------------------
// Kernel 2: per-point MLP via bf16 MFMA, fused concat via rank-3 factorization
// ---------------------------------------------------------------------------
__global__ __launch_bounds__(256) void k_points(
    const float* __restrict__ x,
    const unsigned short* __restrict__ feats_bf,
    const float* __restrict__ rel_in,
    const unsigned short* __restrict__ wbf,
    const float* __restrict__ W0f,       // fp32 W0, rows 320..322 (rel cols)
    const float* __restrict__ b0,
    const float* __restrict__ b1,
    const float* __restrict__ b2,
    float* __restrict__ out_dec)
{
    // LDS: h0 64x264 bf16 (33792 B) | h1 64x264 bf16 (33792, aliased by s 8x256 f32)
    //      xcat 8x336 bf16 (5376) | w3 3x256 f32 (3072) | rl 8x24 f32 (768) = 76800 B
    __shared__ __attribute__((aligned(16))) unsigned short h0s[64 * 264];
    __shared__ __attribute__((aligned(16))) unsigned short h1s[64 * 264];
    __shared__ __attribute__((aligned(16))) unsigned short xcat[NODES2 * 336];
    __shared__ __attribute__((aligned(16))) float w3buf[3 * 256];
    __shared__ __attribute__((aligned(16))) float rl[NODES2 * 24];
    float* s = (float*)h1s;   // [8][256] pre-activation, dead before h1 written

    const int tid  = threadIdx.x;
    const int lane = tid & 63;
    const int w    = tid >> 6;      // wave id 0..3 -> cols [64w, 64w+64)
    const int quad = lane >> 4;     // 0..3
    const int l15  = lane & 15;
    const int blk  = blockIdx.x;
    const size_t nb = (size_t)blk * NODES2;

    // ---- stage inputs (x fp32 -> bf16; feats already bf16)
    for (int e = tid; e < NODES2 * 256; e += 256) {
        int r = e >> 8, c = e & 255;
        xcat[r * 336 + c] = f2bf(x[(nb + r) * 256 + c]);
    }
    {   // 512 u16 = 256 u32 copies, one per thread
        int e = tid * 2;
        int r = e >> 6, c = e & 63;
        *(unsigned int*)&xcat[r * 336 + 256 + c] =
            *(const unsigned int*)&feats_bf[nb * 64 + e];
    }
    for (int e = tid; e < 3 * 256; e += 256) {
        int r = e >> 8, c = e & 255;
        w3buf[e] = W0f[(size_t)(320 + r) * 256 + c];
    }
    if (tid < NODES2 * 24) rl[tid] = rel_in[nb * 24 + tid];
    __syncthreads();

    // ---- layer 0 MFMA: [8(pad16) x 320] @ W0t -> s (pre-relu, pre-rel)
    {
        const unsigned short* W0t = wbf;                    // [256 n][320 k]
        f32x4 acc[4];
        f32x4 z = {0.f, 0.f, 0.f, 0.f};
        #pragma unroll
        for (int t = 0; t < 4; ++t) acc[t] = z;
        const unsigned short* arow = &xcat[(lane & 7) * 336];
        for (int ks = 0; ks < 10; ++ks) {
            int k0 = ks * 32 + quad * 8;
            bf16x8 a = *(const bf16x8*)(arow + k0);
            #pragma unroll
            for (int t = 0; t < 4; ++t) {
                int n = w * 64 + t * 16 + l15;
                bf16x8 b = *(const bf16x8*)(W0t + (size_t)n * 320 + k0);
                acc[t] = __builtin_amdgcn_mfma_f32_16x16x32_bf16(a, b, acc[t], 0, 0, 0);
            }
        }
        #pragma unroll
        for (int t = 0; t < 4; ++t) {
            int col = w * 64 + t * 16 + l15;
            float bb = b0[col];
            #pragma unroll
            for (int r = 0; r < 4; ++r) {
                int row = quad * 4 + r;    // rows 8..15 are duplicates; drop
                if (row < NODES2) s[row * 256 + col] = acc[t][r] + bb;
            }
        }
    }
    __syncthreads();

    // ---- expand s -> h0[64][256] bf16 with rank-3 rel correction + relu
    for (int it = 0; it < 16; ++it) {
        int task = tid + it * 256;          // 64 rows x 64 col-groups
        int row = task >> 6;
        int cg  = task & 63;
        int node = row >> 3, p = row & 7;
        float4 sv = *(const float4*)&s[node * 256 + cg * 4];
        float ra = rl[node * 24 + p * 3 + 0];
        float rb = rl[node * 24 + p * 3 + 1];
        float rc = rl[node * 24 + p * 3 + 2];
        float4 wa = *(const float4*)&w3buf[cg * 4];
        float4 wbv = *(const float4*)&w3buf[256 + cg * 4];
        float4 wc = *(const float4*)&w3buf[512 + cg * 4];
        float v0 = fmaxf(sv.x + ra * wa.x + rb * wbv.x + rc * wc.x, 0.f);
        float v1 = fmaxf(sv.y + ra * wa.y + rb * wbv.y + rc * wc.y, 0.f);
        float v2 = fmaxf(sv.z + ra * wa.z + rb * wbv.z + rc * wc.z, 0.f);
        float v3 = fmaxf(sv.w + ra * wa.w + rb * wbv.w + rc * wc.w, 0.f);
        unsigned int lo = (unsigned int)f2bf(v0) | ((unsigned int)f2bf(v1) << 16);
        unsigned int hi = (unsigned int)f2bf(v2) | ((unsigned int)f2bf(v3) << 16);
        uint2 pk; pk.x = lo; pk.y = hi;
        *(uint2*)&h0s[row * 264 + cg * 4] = pk;
    }
    __syncthreads();

    // ---- FC1: h1 = relu(h0 @ W1 + b1), 64x256 via MFMA
    {
        const unsigned short* W1t = wbf + 81920;            // [256 n][256 k]
        f32x4 acc[4][4];
        f32x4 z = {0.f, 0.f, 0.f, 0.f};
        #pragma unroll
        for (int m = 0; m < 4; ++m)
            #pragma unroll
            for (int t = 0; t < 4; ++t) acc[m][t] = z;
        for (int ks = 0; ks < 8; ++ks) {
            int k0 = ks * 32 + quad * 8;
            bf16x8 a[4], b[4];
            #pragma unroll
            for (int m = 0; m < 4; ++m)
                a[m] = *(const bf16x8*)&h0s[(m * 16 + l15) * 264 + k0];
            #pragma unroll
            for (int t = 0; t < 4; ++t)
                b[t] = *(const bf16x8*)(W1t + (size_t)(w * 64 + t * 16 + l15) * 256 + k0);
            #pragma unroll
            for (int m = 0; m < 4; ++m)
                #pragma unroll
                for (int t = 0; t < 4; ++t)
                    acc[m][t] = __builtin_amdgcn_mfma_f32_16x16x32_bf16(a[m], b[t], acc[m][t], 0, 0, 0);
        }
        #pragma unroll
        for (int t = 0; t < 4; ++t) {
            int col = w * 64 + t * 16 + l15;
            float bb = b1[col];
            #pragma unroll
            for (int m = 0; m < 4; ++m) {
                #pragma unroll
                for (int r = 0; r < 4; ++r) {
                    int row = m * 16 + quad * 4 + r;
                    h1s[row * 264 + col] = f2bf(fmaxf(acc[m][t][r] + bb, 0.f));
                }
            }
        }
    }
    __syncthreads();

    // ---- FC2: out = relu(h1 @ W2 + b2) -> global fp32
    {
        const unsigned short* W2t = wbf + 147456;
        f32x4 acc[4][4];
        f32x4 z = {0.f, 0.f, 0.f, 0.f};
        #pragma unroll
        for (int m = 0; m < 4; ++m)
            #pragma unroll
            for (int t = 0; t < 4; ++t) acc[m][t] = z;
        for (int ks = 0; ks < 8; ++ks) {
            int k0 = ks * 32 + quad * 8;
            bf16x8 a[4], b[4];
            #pragma unroll
            for (int m = 0; m < 4; ++m)
                a[m] = *(const bf16x8*)&h1s[(m * 16 + l15) * 264 + k0];
            #pragma unroll
            for (int t = 0; t < 4; ++t)
                b[t] = *(const bf16x8*)(W2t + (size_t)(w * 64 + t * 16 + l15) * 256 + k0);
            #pragma unroll
            for (int m = 0; m < 4; ++m)
                #pragma unroll
                for (int t = 0; t < 4; ++t)
                    acc[m][t] = __builtin_amdgcn_mfma_f32_16x16x32_bf16(a[m], b[t], acc[m][t], 0, 0, 0);
        }
        #pragma unroll
        for (int t = 0; t < 4; ++t) {
            int col = w * 64 + t * 16 + l15;
            float bb = b2[col];
            #pragma unroll
            for (int m = 0; m < 4; ++m) {
                #pragma unroll
                for (int r = 0; r < 4; ++r) {
                    int row = m * 16 + quad * 4 + r;
                    out_dec[(nb * 8 + row) * 256 + col] = fmaxf(acc[m][t][r] + bb, 0.f);
                }
            }
        }
    }
}

// ---------------------------------------------------------------------------
extern "C" void kernel_launch(void* const* d_in, const int* in_sizes, int n_in,
                              void* d_out, int out_size, void* d_ws, size_t ws_size,
                              hipStream_t stream) {
    const float* x    = (const float*)d_in[0];
    const float* Wg0  = (const float*)d_in[1];
    const float* bg0  = (const float*)d_in[2];
    const float* Wg1  = (const float*)d_in[3];
    const float* bg1  = (const float*)d_in[4];
    const float* Wg2  = (const float*)d_in[5];
    const float* bg2  = (const float*)d_in[6];
    const float* Wdec = (const float*)d_in[7];
    const float* bdec = (const float*)d_in[8];
    const float* W0   = (const float*)d_in[9];
    const float* b0   = (const float*)d_in[10];
    const float* W1   = (const float*)d_in[11];
    const float* b1   = (const float*)d_in[12];
    const float* W2   = (const float*)d_in[13];
    const float* b2   = (const float*)d_in[14];

    float* out      = (float*)d_out;
    float* out_rel  = out;                         // [400000, 3]
    float* out_dec  = out + 1200000;               // [400000, 256]
    float* out_clu  = out + 103600000;             // [400000] as float

    unsigned short* wbf      = (unsigned short*)d_ws;
    unsigned short* feats_bf = wbf + FEATS_OFF;    // [50000, 64] bf16
    unsigned short* gw       = wbf + GW_OFF;       // split global weights

    k_prep<<<1248, 256, 0, stream>>>(W0, W1, W2, Wg0, Wg1, Wg2, wbf);
    k_global<<<NN / TM1, 256, 0, stream>>>(x, bg0, bg1, bg2, Wdec, bdec, gw,
                                           feats_bf, out_rel, out_clu);
    k_points<<<NN / NODES2, 256, 0, stream>>>(x, feats_bf, out_rel,
                                              wbf, W0, b0, b1, b2, out_dec);
}